// Round 5
// baseline (1055.927 us; speedup 1.0000x reference)
//
#include <hip/hip_runtime.h>
#include <hip/hip_bf16.h>
#include <stdint.h>

#define TOKENS 2048
#define HDIM 1024
#define FDIM 3584
#define NEXP 8
#define BK 32

typedef __attribute__((ext_vector_type(8))) short short8;
typedef __attribute__((ext_vector_type(4))) float floatx4;

#define AS1 __attribute__((address_space(1)))
#define AS3 __attribute__((address_space(3)))

__device__ __forceinline__ void glds16(const void* g, void* l) {
  __builtin_amdgcn_global_load_lds((const AS1 void*)g, (AS3 void*)l, 16, 0, 0);
}

__device__ __forceinline__ unsigned short f2bf(float f) {
  union { float f; unsigned int u; } c; c.f = f;
  unsigned int u = c.u;
  u += 0x7fffu + ((u >> 16) & 1u);
  return (unsigned short)(u >> 16);
}

__device__ __forceinline__ unsigned int pk2bf(float a, float b) {
  __hip_bfloat162 h = __float22bfloat162_rn(make_float2(a, b));
  union { __hip_bfloat162 h; unsigned int u; } c; c.h = h;
  return c.u;
}

// ---------------- gating (+ emits xbf for free) ----------------
__global__ void gate_kernel(const float* __restrict__ x,
                            const float* __restrict__ gw,
                            int* __restrict__ top_e,
                            float* __restrict__ top_w,
                            int* __restrict__ count,
                            unsigned short* __restrict__ xbf) {
  int wv = threadIdx.x >> 6;
  int lane = threadIdx.x & 63;
  int t = blockIdx.x * 4 + wv;
  if (t >= TOKENS) return;
  float p[NEXP];
#pragma unroll
  for (int e = 0; e < NEXP; e++) p[e] = 0.f;
  const float* xr = x + (size_t)t * HDIM;
  unsigned short* xb = xbf + (size_t)t * HDIM;
  for (int h = lane; h < HDIM; h += 64) {
    float xv = xr[h];
    xb[h] = f2bf(xv);                       // adjacent lanes -> contiguous stores
    const float4* g4 = (const float4*)(gw + (size_t)h * NEXP);
    float4 a = g4[0], b = g4[1];
    p[0] += xv * a.x; p[1] += xv * a.y; p[2] += xv * a.z; p[3] += xv * a.w;
    p[4] += xv * b.x; p[5] += xv * b.y; p[6] += xv * b.z; p[7] += xv * b.w;
  }
#pragma unroll
  for (int e = 0; e < NEXP; e++) {
#pragma unroll
    for (int off = 32; off > 0; off >>= 1) p[e] += __shfl_xor(p[e], off, 64);
  }
  if (lane == 0) {
    int i0 = 0;
    for (int e = 1; e < NEXP; e++) if (p[e] > p[i0]) i0 = e;
    int i1 = (i0 == 0) ? 1 : 0;
    for (int e = 0; e < NEXP; e++) if (e != i0 && p[e] > p[i1]) i1 = e;
    float l0 = p[i0], l1 = p[i1];
    float e1 = __expf(l1 - l0);
    float s = 1.f + e1;
    top_e[t * 2] = i0; top_e[t * 2 + 1] = i1;
    top_w[t * 2] = 1.f / s; top_w[t * 2 + 1] = e1 / s;
    atomicAdd(&count[i0], 1);
    atomicAdd(&count[i1], 1);
  }
}

// ---------------- route: offsets + scatter fused (single block) ----------------
__global__ void route_kernel(const int* __restrict__ count,
                             const int* __restrict__ top_e,
                             int* __restrict__ offs,
                             int* __restrict__ tok_of,
                             int* __restrict__ slot_of) {
  __shared__ int scur[NEXP];
  if (threadIdx.x == 0) {
    int o = 0;
    for (int e = 0; e < NEXP; e++) { offs[e] = o; scur[e] = o; o += count[e]; }
  }
  __syncthreads();
  for (int t = threadIdx.x; t < TOKENS; t += blockDim.x) {
#pragma unroll
    for (int k = 0; k < 2; k++) {
      int e = top_e[t * 2 + k];
      int g = atomicAdd(&scur[e], 1);
      tok_of[g] = t;
      slot_of[t * 2 + k] = g;
    }
  }
}

// ---------------- GEMM1: act = silu(X w1^T) * (X w3^T), 128x64, dbuf ----------------
// A (bf16) staged via glds; B (fp32) staged via VGPR prefetch + cvt + ds_write.
#define G1_BM 128
#define G1_BF 64

__global__ __launch_bounds__(256, 3)
void gemm1_kernel(const unsigned short* __restrict__ xbf,
                  const float* __restrict__ w1,
                  const float* __restrict__ w3,
                  const int* __restrict__ count,
                  const int* __restrict__ offs,
                  const int* __restrict__ tok_of,
                  unsigned short* __restrict__ act) {
  int e = blockIdx.z;
  int cnt = count[e];
  int m0 = blockIdx.x * G1_BM;
  if (m0 >= cnt) return;
  int f0 = blockIdx.y * G1_BF;
  int off_e = offs[e];

  __shared__ __align__(16) unsigned short sA[2][G1_BM * 32];   // 2 x 8 KB
  __shared__ __align__(16) unsigned short sB1[2][G1_BF * 32];  // 2 x 4 KB
  __shared__ __align__(16) unsigned short sB3[2][G1_BF * 32];  // 2 x 4 KB

  int tid = threadIdx.x;
  int lane = tid & 63, wv = tid >> 6;

  // A staging: 512 chunks of 16B, 2 per thread, chunk-swizzled
  const unsigned short* ag[2];
#pragma unroll
  for (int p = 0; p < 2; p++) {
    int c = tid + p * 256;
    int row = c >> 2, slot = c & 3;
    int gch = slot ^ ((row >> 1) & 3);
    int r = m0 + row;
    int tok = tok_of[off_e + (r < cnt ? r : 0)];
    ag[p] = xbf + (size_t)tok * HDIM + gch * 8;
  }
  unsigned aoff = (unsigned)(wv * 64) * 16;

  // B: fp32, 8 floats per thread per tensor; write bf16 chunk to swizzled slot
  int brow = tid >> 2, bseg = tid & 3;
  const float* b1g = w1 + ((size_t)e * FDIM + f0 + brow) * HDIM + bseg * 8;
  const float* b3g = w3 + ((size_t)e * FDIM + f0 + brow) * HDIM + bseg * 8;
  unsigned bwoff = (unsigned)(brow * 4 + (bseg ^ ((brow >> 1) & 3))) * 16;  // bytes

  int lrow = lane & 15, quad = lane >> 4;
  int wm = wv >> 1, wn = wv & 1;

  floatx4 acc1[4][2], acc3[4][2];
#pragma unroll
  for (int i = 0; i < 4; i++)
#pragma unroll
    for (int j = 0; j < 2; j++) {
      acc1[i][j] = (floatx4){0.f, 0.f, 0.f, 0.f};
      acc3[i][j] = (floatx4){0.f, 0.f, 0.f, 0.f};
    }

  // prologue: tile 0 -> buf 0
#pragma unroll
  for (int p = 0; p < 2; p++)
    glds16(ag[p], (char*)sA[0] + aoff + p * 4096);
  {
    float4 u0 = *(const float4*)(b1g), u1 = *(const float4*)(b1g + 4);
    float4 v0 = *(const float4*)(b3g), v1 = *(const float4*)(b3g + 4);
    uint4 pu, pv;
    pu.x = pk2bf(u0.x, u0.y); pu.y = pk2bf(u0.z, u0.w);
    pu.z = pk2bf(u1.x, u1.y); pu.w = pk2bf(u1.z, u1.w);
    pv.x = pk2bf(v0.x, v0.y); pv.y = pk2bf(v0.z, v0.w);
    pv.z = pk2bf(v1.x, v1.y); pv.w = pk2bf(v1.z, v1.w);
    *(uint4*)((char*)sB1[0] + bwoff) = pu;
    *(uint4*)((char*)sB3[0] + bwoff) = pv;
  }
  __syncthreads();

  int cur = 0;
  for (int k0 = 0; k0 < HDIM; k0 += BK) {
    int kn = k0 + BK;
    int nxt = cur ^ 1;
    float4 u0, u1, v0, v1;
    if (kn < HDIM) {
#pragma unroll
      for (int p = 0; p < 2; p++)
        glds16(ag[p] + kn, (char*)sA[nxt] + aoff + p * 4096);
      u0 = *(const float4*)(b1g + kn); u1 = *(const float4*)(b1g + kn + 4);
      v0 = *(const float4*)(b3g + kn); v1 = *(const float4*)(b3g + kn + 4);
    }

    short8 af[4], b1f[2], b3f[2];
#pragma unroll
    for (int ms = 0; ms < 4; ms++) {
      int r = wm * 64 + ms * 16 + lrow;
      int sl = quad ^ ((r >> 1) & 3);
      af[ms] = *(const short8*)(sA[cur] + r * 32 + sl * 8);
    }
#pragma unroll
    for (int ns = 0; ns < 2; ns++) {
      int r = wn * 32 + ns * 16 + lrow;
      int sl = quad ^ ((r >> 1) & 3);
      b1f[ns] = *(const short8*)(sB1[cur] + r * 32 + sl * 8);
      b3f[ns] = *(const short8*)(sB3[cur] + r * 32 + sl * 8);
    }
#pragma unroll
    for (int ms = 0; ms < 4; ms++)
#pragma unroll
      for (int ns = 0; ns < 2; ns++) {
        acc1[ms][ns] = __builtin_amdgcn_mfma_f32_16x16x32_bf16(af[ms], b1f[ns], acc1[ms][ns], 0, 0, 0);
        acc3[ms][ns] = __builtin_amdgcn_mfma_f32_16x16x32_bf16(af[ms], b3f[ns], acc3[ms][ns], 0, 0, 0);
      }

    if (kn < HDIM) {   // convert after MFMA section (load latency covered)
      uint4 pu, pv;
      pu.x = pk2bf(u0.x, u0.y); pu.y = pk2bf(u0.z, u0.w);
      pu.z = pk2bf(u1.x, u1.y); pu.w = pk2bf(u1.z, u1.w);
      pv.x = pk2bf(v0.x, v0.y); pv.y = pk2bf(v0.z, v0.w);
      pv.z = pk2bf(v1.x, v1.y); pv.w = pk2bf(v1.z, v1.w);
      *(uint4*)((char*)sB1[nxt] + bwoff) = pu;
      *(uint4*)((char*)sB3[nxt] + bwoff) = pv;
    }
    __syncthreads();
    cur ^= 1;
  }

#pragma unroll
  for (int ms = 0; ms < 4; ms++) {
#pragma unroll
    for (int reg = 0; reg < 4; reg++) {
      int slot = m0 + wm * 64 + ms * 16 + quad * 4 + reg;
      if (slot < cnt) {
        unsigned short* ar = act + (size_t)(off_e + slot) * FDIM + f0 + wn * 32;
#pragma unroll
        for (int ns = 0; ns < 2; ns++) {
          float h = acc1[ms][ns][reg];
          float g = acc3[ms][ns][reg];
          float a = h / (1.f + __expf(-h)) * g;
          ar[ns * 16 + lrow] = f2bf(a);
        }
      }
    }
  }
}

// ---------------- GEMM2: part[sk] = act w2^T (K-slice), 128x128, dbuf ----------------
#define G2_BM 128
#define G2_BN 128
#define SPLITK 4
#define G2_KS (FDIM / SPLITK)   // 896

__global__ __launch_bounds__(256, 3)
void gemm2_kernel(const unsigned short* __restrict__ act,
                  const float* __restrict__ w2,
                  const int* __restrict__ count,
                  const int* __restrict__ offs,
                  float* __restrict__ part) {
  int zz = blockIdx.z;
  int e = zz & 7, sk = zz >> 3;
  int cnt = count[e];
  int m0 = blockIdx.x * G2_BM;
  if (m0 >= cnt) return;
  int h0 = blockIdx.y * G2_BN;
  int off_e = offs[e];
  int kb = sk * G2_KS;

  __shared__ __align__(16) unsigned short sA[2][G2_BM * 32];  // 2 x 8 KB
  __shared__ __align__(16) unsigned short sB[2][G2_BN * 32];  // 2 x 8 KB

  int tid = threadIdx.x;
  int lane = tid & 63, wv = tid >> 6;

  // A staging via glds (act is bf16)
  const unsigned short* ag[2];
#pragma unroll
  for (int p = 0; p < 2; p++) {
    int c = tid + p * 256;
    int row = c >> 2, slot = c & 3;
    int gch = slot ^ ((row >> 1) & 3);
    int r = m0 + row;
    int rr = (r < cnt ? r : 0);
    ag[p] = act + (size_t)(off_e + rr) * FDIM + kb + gch * 8;
  }
  unsigned aoff = (unsigned)(wv * 64) * 16;

  // B staging: fp32, 2 tasks per thread (rows r and r+64), 8 floats each
  const float* bg[2];
  unsigned bwoff[2];
#pragma unroll
  for (int p = 0; p < 2; p++) {
    int c = tid + p * 256;
    int row = c >> 2, seg = c & 3;
    bg[p] = w2 + ((size_t)e * HDIM + h0 + row) * FDIM + kb + seg * 8;
    bwoff[p] = (unsigned)(row * 4 + (seg ^ ((row >> 1) & 3))) * 16;
  }

  int lrow = lane & 15, quad = lane >> 4;
  int wm = wv >> 1, wn = wv & 1;

  floatx4 acc[4][4];
#pragma unroll
  for (int i = 0; i < 4; i++)
#pragma unroll
    for (int j = 0; j < 4; j++) acc[i][j] = (floatx4){0.f, 0.f, 0.f, 0.f};

  // prologue
#pragma unroll
  for (int p = 0; p < 2; p++) {
    glds16(ag[p], (char*)sA[0] + aoff + p * 4096);
    float4 u0 = *(const float4*)(bg[p]), u1 = *(const float4*)(bg[p] + 4);
    uint4 pu;
    pu.x = pk2bf(u0.x, u0.y); pu.y = pk2bf(u0.z, u0.w);
    pu.z = pk2bf(u1.x, u1.y); pu.w = pk2bf(u1.z, u1.w);
    *(uint4*)((char*)sB[0] + bwoff[p]) = pu;
  }
  __syncthreads();

  int cur = 0;
  for (int k0 = 0; k0 < G2_KS; k0 += BK) {
    int kn = k0 + BK;
    int nxt = cur ^ 1;
    float4 u0[2], u1[2];
    if (kn < G2_KS) {
#pragma unroll
      for (int p = 0; p < 2; p++) {
        glds16(ag[p] + kn, (char*)sA[nxt] + aoff + p * 4096);
        u0[p] = *(const float4*)(bg[p] + kn);
        u1[p] = *(const float4*)(bg[p] + kn + 4);
      }
    }

    short8 af[4], bf[4];
#pragma unroll
    for (int ms = 0; ms < 4; ms++) {
      int r = wm * 64 + ms * 16 + lrow;
      int sl = quad ^ ((r >> 1) & 3);
      af[ms] = *(const short8*)(sA[cur] + r * 32 + sl * 8);
    }
#pragma unroll
    for (int ns = 0; ns < 4; ns++) {
      int r = wn * 64 + ns * 16 + lrow;
      int sl = quad ^ ((r >> 1) & 3);
      bf[ns] = *(const short8*)(sB[cur] + r * 32 + sl * 8);
    }
#pragma unroll
    for (int ms = 0; ms < 4; ms++)
#pragma unroll
      for (int ns = 0; ns < 4; ns++)
        acc[ms][ns] = __builtin_amdgcn_mfma_f32_16x16x32_bf16(af[ms], bf[ns], acc[ms][ns], 0, 0, 0);

    if (kn < G2_KS) {
#pragma unroll
      for (int p = 0; p < 2; p++) {
        uint4 pu;
        pu.x = pk2bf(u0[p].x, u0[p].y); pu.y = pk2bf(u0[p].z, u0[p].w);
        pu.z = pk2bf(u1[p].x, u1[p].y); pu.w = pk2bf(u1[p].z, u1[p].w);
        *(uint4*)((char*)sB[nxt] + bwoff[p]) = pu;
      }
    }
    __syncthreads();
    cur ^= 1;
  }

#pragma unroll
  for (int ms = 0; ms < 4; ms++) {
#pragma unroll
    for (int reg = 0; reg < 4; reg++) {
      int slot = m0 + wm * 64 + ms * 16 + quad * 4 + reg;
      if (slot < cnt) {
        float* crow = part + ((size_t)sk * 4096 + off_e + slot) * HDIM + h0 + wn * 64;
#pragma unroll
        for (int ns = 0; ns < 4; ns++)
          crow[ns * 16 + lrow] = acc[ms][ns][reg];
      }
    }
  }
}

// ---------------- combine ----------------
__global__ void combine_kernel(const float* __restrict__ part,
                               const int* __restrict__ slot_of,
                               const float* __restrict__ top_w,
                               float* __restrict__ out) {
  int t = blockIdx.x;
  int g0 = slot_of[t * 2], g1 = slot_of[t * 2 + 1];
  float w0 = top_w[t * 2], w1 = top_w[t * 2 + 1];
  int i = threadIdx.x;
  float4 s0 = {0.f, 0.f, 0.f, 0.f}, s1 = {0.f, 0.f, 0.f, 0.f};
#pragma unroll
  for (int sk = 0; sk < SPLITK; sk++) {
    float4 a = ((const float4*)(part + ((size_t)sk * 4096 + g0) * HDIM))[i];
    float4 b = ((const float4*)(part + ((size_t)sk * 4096 + g1) * HDIM))[i];
    s0.x += a.x; s0.y += a.y; s0.z += a.z; s0.w += a.w;
    s1.x += b.x; s1.y += b.y; s1.z += b.z; s1.w += b.w;
  }
  float4 r;
  r.x = w0 * s0.x + w1 * s1.x;
  r.y = w0 * s0.y + w1 * s1.y;
  r.z = w0 * s0.z + w1 * s1.z;
  r.w = w0 * s0.w + w1 * s1.w;
  ((float4*)(out + (size_t)t * HDIM))[i] = r;
}

// ---------------- launcher ----------------
extern "C" void kernel_launch(void* const* d_in, const int* in_sizes, int n_in,
                              void* d_out, int out_size, void* d_ws, size_t ws_size,
                              hipStream_t stream) {
  const float* x  = (const float*)d_in[0];
  const float* gw = (const float*)d_in[1];
  const float* w1 = (const float*)d_in[2];
  const float* w3 = (const float*)d_in[3];
  const float* w2 = (const float*)d_in[4];
  float* out = (float*)d_out;

  char* ws = (char*)d_ws;
  // layout: act [0,28M) | xbf [28M,32M) | part [32M,96M) | small [96M,..)
  unsigned short* act = (unsigned short*)(ws);
  unsigned short* xbf = (unsigned short*)(ws + (28ull << 20));
  float* part = (float*)(ws + (32ull << 20));
  char* sml = ws + (96ull << 20);
  float* top_w = (float*)sml;
  int* top_e   = (int*)(sml + 16384);
  int* slot_of = (int*)(sml + 32768);
  int* tok_of  = (int*)(sml + 49152);
  int* count   = (int*)(sml + 65536);
  int* offs    = (int*)(sml + 65536 + 64);

  hipMemsetAsync(count, 0, 64, stream);

  gate_kernel<<<TOKENS / 4, 256, 0, stream>>>(x, gw, top_e, top_w, count, xbf);
  route_kernel<<<1, 1024, 0, stream>>>(count, top_e, offs, tok_of, slot_of);
  gemm1_kernel<<<dim3(TOKENS / G1_BM, FDIM / G1_BF, NEXP), 256, 0, stream>>>(
      xbf, w1, w3, count, offs, tok_of, act);
  gemm2_kernel<<<dim3(TOKENS / G2_BM, HDIM / G2_BN, NEXP * SPLITK), 256, 0, stream>>>(
      act, w2, count, offs, part);
  combine_kernel<<<TOKENS, 256, 0, stream>>>(part, slot_of, top_w, out);
}